// Round 1
// baseline (3246.310 us; speedup 1.0000x reference)
//
#include <hip/hip_runtime.h>

#define NN   50000
#define IN_F 128
#define HF   256
#define COUT 64
#define MLPH 128
#define EG   600000
#define EK   800000
#define BN_EPS 1e-5f

// ---------------- degree ----------------
__global__ __launch_bounds__(256) void deg_kernel(const int* __restrict__ dst, int E,
                                                  float* __restrict__ deg) {
  int e = blockIdx.x * 256 + threadIdx.x;
  if (e < E) atomicAdd(&deg[dst[e]], 1.0f);
}

__global__ __launch_bounds__(256) void invdeg_kernel(float* __restrict__ deg) {
  int i = blockIdx.x * 256 + threadIdx.x;
  if (i < NN) deg[i] = 1.0f / fmaxf(deg[i], 1.0f);
}

// ---------------- aggregation: agg[dst] += h[src] ----------------
template <int DLOG2>
__global__ __launch_bounds__(256) void aggregate_kernel(const float* __restrict__ h,
                                                        const int* __restrict__ src,
                                                        const int* __restrict__ dst,
                                                        float* __restrict__ agg, int E) {
  int gi = blockIdx.x * 256 + threadIdx.x;
  int e = gi >> DLOG2;
  int f = gi & ((1 << DLOG2) - 1);
  if (e < E) {
    int s = src[e], d = dst[e];
    atomicAdd(&agg[(d << DLOG2) + f], h[(s << DLOG2) + f]);
  }
}

// ---------------- fused dual-GEMM ----------------
// out[m, n] = act( sum_k A1[m,k] B1[k,n]  +  sum_k (A2[m,k]*inv2[m]) B2[k,n] + bias[n] )
// BN1: A1 element transformed as relu(A1*bnscale[k] + bnshift[k]) on load.
template <int K1, int K2, bool RELU, bool SCALE2, bool BN1>
__global__ __launch_bounds__(256) void gemm_fused(
    const float* __restrict__ A1, const float* __restrict__ A2,
    const float* __restrict__ inv2, const float* __restrict__ B1,
    const float* __restrict__ B2, int ldb, const float* __restrict__ bias,
    const float* __restrict__ bnscale, const float* __restrict__ bnshift,
    float* __restrict__ out, int ldo, int nrows) {
  constexpr int BM = 64, BN = 64, BK = 32;
  constexpr int KT = (K1 + K2) / BK;
  __shared__ float As[BK][BM + 4];  // [k][m]
  __shared__ float Bs[BK][BN + 4];  // [k][n]
  const int t = threadIdx.x;
  const int tx = t & 15, ty = t >> 4;
  const int row0 = blockIdx.y * BM;
  const int n0 = blockIdx.x * BN;

  float acc[4][4] = {};

  for (int kt = 0; kt < KT; ++kt) {
    const int kbase = kt * BK;
    const bool fromA1 = (kbase < K1);
    const float* Asrc = fromA1 ? A1 : A2;
    const int kA = fromA1 ? kbase : (kbase - K1);
    const int lda = fromA1 ? K1 : K2;

    // ---- A tile: 64 rows x 32 k, as float4 ----
#pragma unroll
    for (int it = 0; it < 2; ++it) {
      int idx = t + it * 256;
      int r = idx >> 3;
      int kq = (idx & 7) * 4;
      int rg = row0 + r;
      if (rg >= nrows) rg = nrows - 1;
      float4 v = *reinterpret_cast<const float4*>(&Asrc[(size_t)rg * lda + kA + kq]);
      if (SCALE2 && !fromA1) {
        float s = inv2[rg];
        v.x *= s; v.y *= s; v.z *= s; v.w *= s;
      }
      if (BN1 && fromA1) {
        v.x = fmaxf(v.x * bnscale[kA + kq + 0] + bnshift[kA + kq + 0], 0.f);
        v.y = fmaxf(v.y * bnscale[kA + kq + 1] + bnshift[kA + kq + 1], 0.f);
        v.z = fmaxf(v.z * bnscale[kA + kq + 2] + bnshift[kA + kq + 2], 0.f);
        v.w = fmaxf(v.w * bnscale[kA + kq + 3] + bnshift[kA + kq + 3], 0.f);
      }
      As[kq + 0][r] = v.x;
      As[kq + 1][r] = v.y;
      As[kq + 2][r] = v.z;
      As[kq + 3][r] = v.w;
    }
    // ---- B tile: 32 k x 64 n ----
    const float* Bsrc = fromA1 ? B1 : B2;
#pragma unroll
    for (int it = 0; it < 2; ++it) {
      int idx = t + it * 256;
      int br = idx >> 4;
      int bq = (idx & 15) * 4;
      float4 v = *reinterpret_cast<const float4*>(&Bsrc[(size_t)(kA + br) * ldb + n0 + bq]);
      *reinterpret_cast<float4*>(&Bs[br][bq]) = v;
    }
    __syncthreads();

#pragma unroll
    for (int kk = 0; kk < BK; ++kk) {
      float4 av = *reinterpret_cast<const float4*>(&As[kk][ty * 4]);
      float4 bv = *reinterpret_cast<const float4*>(&Bs[kk][tx * 4]);
      float a0 = av.x, a1 = av.y, a2 = av.z, a3 = av.w;
      float b0 = bv.x, b1 = bv.y, b2 = bv.z, b3 = bv.w;
      acc[0][0] += a0 * b0; acc[0][1] += a0 * b1; acc[0][2] += a0 * b2; acc[0][3] += a0 * b3;
      acc[1][0] += a1 * b0; acc[1][1] += a1 * b1; acc[1][2] += a1 * b2; acc[1][3] += a1 * b3;
      acc[2][0] += a2 * b0; acc[2][1] += a2 * b1; acc[2][2] += a2 * b2; acc[2][3] += a2 * b3;
      acc[3][0] += a3 * b0; acc[3][1] += a3 * b1; acc[3][2] += a3 * b2; acc[3][3] += a3 * b3;
    }
    __syncthreads();
  }

  // ---- epilogue ----
#pragma unroll
  for (int i = 0; i < 4; ++i) {
    int r = row0 + ty * 4 + i;
    if (r < nrows) {
      float4 o;
      o.x = acc[i][0] + bias[n0 + tx * 4 + 0];
      o.y = acc[i][1] + bias[n0 + tx * 4 + 1];
      o.z = acc[i][2] + bias[n0 + tx * 4 + 2];
      o.w = acc[i][3] + bias[n0 + tx * 4 + 3];
      if (RELU) {
        o.x = fmaxf(o.x, 0.f); o.y = fmaxf(o.y, 0.f);
        o.z = fmaxf(o.z, 0.f); o.w = fmaxf(o.w, 0.f);
      }
      *reinterpret_cast<float4*>(&out[(size_t)r * ldo + n0 + tx * 4]) = o;
    }
  }
}

// ---------------- BN stats over columns of x[N, 128] ----------------
__global__ __launch_bounds__(256) void bn_stats_kernel(const float* __restrict__ x,
                                                       float* __restrict__ sums,
                                                       float* __restrict__ sumsq) {
  int c = threadIdx.x & 127;
  int rbase = (blockIdx.x * 256 + threadIdx.x) >> 7;
  int stride = (gridDim.x * 256) >> 7;
  float s = 0.f, s2 = 0.f;
  for (int r = rbase; r < NN; r += stride) {
    float v = x[(size_t)r * 128 + c];
    s += v;
    s2 += v * v;
  }
  __shared__ float ls[256], ls2[256];
  ls[threadIdx.x] = s;
  ls2[threadIdx.x] = s2;
  __syncthreads();
  if (threadIdx.x < 128) {
    s = ls[threadIdx.x] + ls[threadIdx.x + 128];
    s2 = ls2[threadIdx.x] + ls2[threadIdx.x + 128];
    atomicAdd(&sums[c], s);
    atomicAdd(&sumsq[c], s2);
  }
}

__global__ __launch_bounds__(128) void bn_finalize_kernel(float* __restrict__ stats,
                                                          const float* __restrict__ gamma,
                                                          const float* __restrict__ beta) {
  int c = threadIdx.x;
  float mu = stats[c] * (1.0f / NN);
  float var = stats[128 + c] * (1.0f / NN) - mu * mu;
  var = fmaxf(var, 0.f);
  float sc = gamma[c] * rsqrtf(var + BN_EPS);
  stats[256 + c] = sc;
  stats[384 + c] = beta[c] - mu * sc;
}

// ---------------- launch ----------------
extern "C" void kernel_launch(void* const* d_in, const int* in_sizes, int n_in,
                              void* d_out, int out_size, void* d_ws, size_t ws_size,
                              hipStream_t stream) {
  const float* feat = (const float*)d_in[0];
  const int* g_src = (const int*)d_in[1];
  const int* g_dst = (const int*)d_in[2];
  const int* k_src = (const int*)d_in[3];
  const int* k_dst = (const int*)d_in[4];
  const float* lw_self_0 = (const float*)d_in[5];
  const float* lw_neigh_0 = (const float*)d_in[6];
  const float* lb_0 = (const float*)d_in[7];
  const float* lw_self_1 = (const float*)d_in[8];
  const float* lw_neigh_1 = (const float*)d_in[9];
  const float* lb_1 = (const float*)d_in[10];
  const float* lw_self_2 = (const float*)d_in[11];
  const float* lw_neigh_2 = (const float*)d_in[12];
  const float* lb_2 = (const float*)d_in[13];
  const float* gw_self_0 = (const float*)d_in[14];
  const float* gw_neigh_0 = (const float*)d_in[15];
  const float* gb_0 = (const float*)d_in[16];
  const float* gw_self_1 = (const float*)d_in[17];
  const float* gw_neigh_1 = (const float*)d_in[18];
  const float* gb_1 = (const float*)d_in[19];
  const float* mlp_w1 = (const float*)d_in[20];
  const float* mlp_b1 = (const float*)d_in[21];
  const float* bn_gamma = (const float*)d_in[22];
  const float* bn_beta = (const float*)d_in[23];
  const float* mlp_w2 = (const float*)d_in[24];
  const float* mlp_b2 = (const float*)d_in[25];
  float* out = (float*)d_out;

  float* ws = (float*)d_ws;
  float* bufA = ws;                          // N*H
  float* bufB = bufA + (size_t)NN * HF;      // N*H
  float* bufC = bufB + (size_t)NN * HF;      // N*H  (agg scratch, then x)
  float* bufD = bufC + (size_t)NN * HF;      // N*H  (local_emb)
  float* invg = bufD + (size_t)NN * HF;      // N
  float* invk = invg + NN;                   // N
  float* stats = invk + NN;                  // 512: sums, sumsq, scale, shift

  dim3 blk(256);
  const dim3 gridH(HF / 64, (NN + 63) / 64);    // 256-col outputs
  const dim3 gridM(MLPH / 64, (NN + 63) / 64);  // 128-col outputs
  const dim3 gridO(COUT / 64, (NN + 63) / 64);  // 64-col outputs

  // degrees -> inverse degrees
  hipMemsetAsync(invg, 0, NN * sizeof(float), stream);
  hipMemsetAsync(invk, 0, NN * sizeof(float), stream);
  deg_kernel<<<(EG + 255) / 256, blk, 0, stream>>>(g_dst, EG, invg);
  deg_kernel<<<(EK + 255) / 256, blk, 0, stream>>>(k_dst, EK, invk);
  invdeg_kernel<<<(NN + 255) / 256, blk, 0, stream>>>(invg);
  invdeg_kernel<<<(NN + 255) / 256, blk, 0, stream>>>(invk);

  // ---- local layer 0: feat[N,128] -> bufA[N,256], relu ----
  hipMemsetAsync(bufC, 0, (size_t)NN * IN_F * sizeof(float), stream);
  aggregate_kernel<7><<<EG * IN_F / 256, blk, 0, stream>>>(feat, g_src, g_dst, bufC, EG);
  gemm_fused<128, 128, true, true, false><<<gridH, blk, 0, stream>>>(
      feat, bufC, invg, lw_self_0, lw_neigh_0, HF, lb_0, nullptr, nullptr, bufA, HF, NN);

  // ---- local layer 1: bufA -> bufB, relu ----
  hipMemsetAsync(bufC, 0, (size_t)NN * HF * sizeof(float), stream);
  aggregate_kernel<8><<<EG * HF / 256, blk, 0, stream>>>(bufA, g_src, g_dst, bufC, EG);
  gemm_fused<256, 256, true, true, false><<<gridH, blk, 0, stream>>>(
      bufA, bufC, invg, lw_self_1, lw_neigh_1, HF, lb_1, nullptr, nullptr, bufB, HF, NN);

  // ---- local layer 2: bufB -> bufD (local_emb), no relu ----
  hipMemsetAsync(bufC, 0, (size_t)NN * HF * sizeof(float), stream);
  aggregate_kernel<8><<<EG * HF / 256, blk, 0, stream>>>(bufB, g_src, g_dst, bufC, EG);
  gemm_fused<256, 256, false, true, false><<<gridH, blk, 0, stream>>>(
      bufB, bufC, invg, lw_self_2, lw_neigh_2, HF, lb_2, nullptr, nullptr, bufD, HF, NN);

  // ---- global layer 0: feat -> bufA, relu ----
  hipMemsetAsync(bufC, 0, (size_t)NN * IN_F * sizeof(float), stream);
  aggregate_kernel<7><<<EK * IN_F / 256, blk, 0, stream>>>(feat, k_src, k_dst, bufC, EK);
  gemm_fused<128, 128, true, true, false><<<gridH, blk, 0, stream>>>(
      feat, bufC, invk, gw_self_0, gw_neigh_0, HF, gb_0, nullptr, nullptr, bufA, HF, NN);

  // ---- global layer 1: bufA -> bufB (global_emb), no relu ----
  hipMemsetAsync(bufC, 0, (size_t)NN * HF * sizeof(float), stream);
  aggregate_kernel<8><<<EK * HF / 256, blk, 0, stream>>>(bufA, k_src, k_dst, bufC, EK);
  gemm_fused<256, 256, false, true, false><<<gridH, blk, 0, stream>>>(
      bufA, bufC, invk, gw_self_1, gw_neigh_1, HF, gb_1, nullptr, nullptr, bufB, HF, NN);

  // ---- head GEMM1: x = local_emb @ w1[0:256] + global_emb @ w1[256:512] + b1 ----
  gemm_fused<256, 256, false, false, false><<<gridM, blk, 0, stream>>>(
      bufD, bufB, nullptr, mlp_w1, mlp_w1 + 256 * MLPH, MLPH, mlp_b1, nullptr, nullptr,
      bufC, MLPH, NN);

  // ---- BatchNorm stats + finalize ----
  hipMemsetAsync(stats, 0, 2 * 128 * sizeof(float), stream);
  bn_stats_kernel<<<256, blk, 0, stream>>>(bufC, stats, stats + 128);
  bn_finalize_kernel<<<1, 128, 0, stream>>>(stats, bn_gamma, bn_beta);

  // ---- head GEMM2: out = relu(bn(x)) @ w2 + b2 ----
  gemm_fused<128, 0, false, false, true><<<gridO, blk, 0, stream>>>(
      bufC, nullptr, nullptr, mlp_w2, nullptr, COUT, mlp_b2, stats + 256, stats + 384,
      out, COUT, NN);
}

// Round 2
// 1502.921 us; speedup vs baseline: 2.1600x; 2.1600x over previous
//
#include <hip/hip_runtime.h>

#define NN   50000
#define IN_F 128
#define HF   256
#define COUT 64
#define MLPH 128
#define EG   600000
#define EK   800000
#define BN_EPS 1e-5f

// ---------------- CSR build ----------------
__global__ __launch_bounds__(256) void count_kernel(const int* __restrict__ dst, int E,
                                                    int* __restrict__ cnt) {
  int e = blockIdx.x * 256 + threadIdx.x;
  if (e < E) atomicAdd(&cnt[dst[e]], 1);
}

__global__ __launch_bounds__(256) void invdeg_kernel(const int* __restrict__ cnt,
                                                     float* __restrict__ inv) {
  int i = blockIdx.x * 256 + threadIdx.x;
  if (i < NN) inv[i] = 1.0f / fmaxf((float)cnt[i], 1.0f);
}

// single-block exclusive scan of cnt[0..n) -> off[0..n]
__global__ __launch_bounds__(1024) void scan_kernel(const int* __restrict__ cnt,
                                                    int* __restrict__ off, int n) {
  __shared__ int wsum[16];
  __shared__ int carry_s;
  const int tid = threadIdx.x;
  const int wid = tid >> 6, lane = tid & 63;
  if (tid == 0) carry_s = 0;
  __syncthreads();
  for (int base = 0; base < n; base += 1024) {
    int i = base + tid;
    int v = (i < n) ? cnt[i] : 0;
    int x = v;
#pragma unroll
    for (int d = 1; d < 64; d <<= 1) {
      int y = __shfl_up(x, d, 64);
      if (lane >= d) x += y;
    }
    if (lane == 63) wsum[wid] = x;
    __syncthreads();
    if (wid == 0 && lane < 16) {
      int s = wsum[lane];
#pragma unroll
      for (int d = 1; d < 16; d <<= 1) {
        int y = __shfl_up(s, d, 16);
        if (lane >= d) s += y;
      }
      wsum[lane] = s;
    }
    __syncthreads();
    int block_excl = (wid > 0) ? wsum[wid - 1] : 0;
    int incl = x + block_excl + carry_s;
    if (i < n) off[i] = incl - v;
    __syncthreads();
    if (tid == 0) carry_s += wsum[15];
    __syncthreads();
  }
  if (tid == 0) off[n] = carry_s;
}

__global__ __launch_bounds__(256) void fill_kernel(const int* __restrict__ src,
                                                   const int* __restrict__ dst, int E,
                                                   const int* __restrict__ off,
                                                   int* __restrict__ cursor,
                                                   int* __restrict__ esrc) {
  int e = blockIdx.x * 256 + threadIdx.x;
  if (e < E) {
    int d = dst[e];
    int p = atomicAdd(&cursor[d], 1);
    esrc[off[d] + p] = src[e];
  }
}

// ---------------- CSR aggregation: agg[v] = sum_{u in N(v)} h[u] ----------------
template <int DLOG2>
__global__ __launch_bounds__(256) void csr_aggregate(const float* __restrict__ h,
                                                     const int* __restrict__ off,
                                                     const int* __restrict__ esrc,
                                                     float* __restrict__ agg) {
  constexpr int TPN = (1 << DLOG2) >> 2;  // threads per node (float4 each)
  constexpr int NPB = 256 / TPN;
  int node = blockIdx.x * NPB + (threadIdx.x / TPN);
  int lane = threadIdx.x & (TPN - 1);
  if (node >= NN) return;
  int s = off[node], e = off[node + 1];
  float4 acc = {0.f, 0.f, 0.f, 0.f};
  int j = s;
  for (; j + 1 < e; j += 2) {
    int s0 = esrc[j], s1 = esrc[j + 1];
    float4 v0 = *reinterpret_cast<const float4*>(&h[((size_t)s0 << DLOG2) + (lane << 2)]);
    float4 v1 = *reinterpret_cast<const float4*>(&h[((size_t)s1 << DLOG2) + (lane << 2)]);
    acc.x += v0.x; acc.y += v0.y; acc.z += v0.z; acc.w += v0.w;
    acc.x += v1.x; acc.y += v1.y; acc.z += v1.z; acc.w += v1.w;
  }
  if (j < e) {
    int s0 = esrc[j];
    float4 v0 = *reinterpret_cast<const float4*>(&h[((size_t)s0 << DLOG2) + (lane << 2)]);
    acc.x += v0.x; acc.y += v0.y; acc.z += v0.z; acc.w += v0.w;
  }
  *reinterpret_cast<float4*>(&agg[((size_t)node << DLOG2) + (lane << 2)]) = acc;
}

// ---------------- fused dual-GEMM ----------------
// out[m, n] = act( sum_k A1[m,k] B1[k,n]  +  sum_k (A2[m,k]*inv2[m]) B2[k,n] + bias[n] )
// BN1: A1 element transformed as relu(A1*bnscale[k] + bnshift[k]) on load.
template <int K1, int K2, bool RELU, bool SCALE2, bool BN1>
__global__ __launch_bounds__(256) void gemm_fused(
    const float* __restrict__ A1, const float* __restrict__ A2,
    const float* __restrict__ inv2, const float* __restrict__ B1,
    const float* __restrict__ B2, int ldb, const float* __restrict__ bias,
    const float* __restrict__ bnscale, const float* __restrict__ bnshift,
    float* __restrict__ out, int ldo, int nrows) {
  constexpr int BM = 64, BN = 64, BK = 32;
  constexpr int KT = (K1 + K2) / BK;
  __shared__ float As[BK][BM + 4];  // [k][m]
  __shared__ float Bs[BK][BN + 4];  // [k][n]
  const int t = threadIdx.x;
  const int tx = t & 15, ty = t >> 4;
  const int row0 = blockIdx.y * BM;
  const int n0 = blockIdx.x * BN;

  float acc[4][4] = {};

  for (int kt = 0; kt < KT; ++kt) {
    const int kbase = kt * BK;
    const bool fromA1 = (kbase < K1);
    const float* Asrc = fromA1 ? A1 : A2;
    const int kA = fromA1 ? kbase : (kbase - K1);
    const int lda = fromA1 ? K1 : K2;

#pragma unroll
    for (int it = 0; it < 2; ++it) {
      int idx = t + it * 256;
      int r = idx >> 3;
      int kq = (idx & 7) * 4;
      int rg = row0 + r;
      if (rg >= nrows) rg = nrows - 1;
      float4 v = *reinterpret_cast<const float4*>(&Asrc[(size_t)rg * lda + kA + kq]);
      if (SCALE2 && !fromA1) {
        float s = inv2[rg];
        v.x *= s; v.y *= s; v.z *= s; v.w *= s;
      }
      if (BN1 && fromA1) {
        v.x = fmaxf(v.x * bnscale[kA + kq + 0] + bnshift[kA + kq + 0], 0.f);
        v.y = fmaxf(v.y * bnscale[kA + kq + 1] + bnshift[kA + kq + 1], 0.f);
        v.z = fmaxf(v.z * bnscale[kA + kq + 2] + bnshift[kA + kq + 2], 0.f);
        v.w = fmaxf(v.w * bnscale[kA + kq + 3] + bnshift[kA + kq + 3], 0.f);
      }
      As[kq + 0][r] = v.x;
      As[kq + 1][r] = v.y;
      As[kq + 2][r] = v.z;
      As[kq + 3][r] = v.w;
    }
    const float* Bsrc = fromA1 ? B1 : B2;
#pragma unroll
    for (int it = 0; it < 2; ++it) {
      int idx = t + it * 256;
      int br = idx >> 4;
      int bq = (idx & 15) * 4;
      float4 v = *reinterpret_cast<const float4*>(&Bsrc[(size_t)(kA + br) * ldb + n0 + bq]);
      *reinterpret_cast<float4*>(&Bs[br][bq]) = v;
    }
    __syncthreads();

#pragma unroll
    for (int kk = 0; kk < BK; ++kk) {
      float4 av = *reinterpret_cast<const float4*>(&As[kk][ty * 4]);
      float4 bv = *reinterpret_cast<const float4*>(&Bs[kk][tx * 4]);
      float a0 = av.x, a1 = av.y, a2 = av.z, a3 = av.w;
      float b0 = bv.x, b1 = bv.y, b2 = bv.z, b3 = bv.w;
      acc[0][0] += a0 * b0; acc[0][1] += a0 * b1; acc[0][2] += a0 * b2; acc[0][3] += a0 * b3;
      acc[1][0] += a1 * b0; acc[1][1] += a1 * b1; acc[1][2] += a1 * b2; acc[1][3] += a1 * b3;
      acc[2][0] += a2 * b0; acc[2][1] += a2 * b1; acc[2][2] += a2 * b2; acc[2][3] += a2 * b3;
      acc[3][0] += a3 * b0; acc[3][1] += a3 * b1; acc[3][2] += a3 * b2; acc[3][3] += a3 * b3;
    }
    __syncthreads();
  }

#pragma unroll
  for (int i = 0; i < 4; ++i) {
    int r = row0 + ty * 4 + i;
    if (r < nrows) {
      float4 o;
      o.x = acc[i][0] + bias[n0 + tx * 4 + 0];
      o.y = acc[i][1] + bias[n0 + tx * 4 + 1];
      o.z = acc[i][2] + bias[n0 + tx * 4 + 2];
      o.w = acc[i][3] + bias[n0 + tx * 4 + 3];
      if (RELU) {
        o.x = fmaxf(o.x, 0.f); o.y = fmaxf(o.y, 0.f);
        o.z = fmaxf(o.z, 0.f); o.w = fmaxf(o.w, 0.f);
      }
      *reinterpret_cast<float4*>(&out[(size_t)r * ldo + n0 + tx * 4]) = o;
    }
  }
}

// ---------------- BN stats over columns of x[N, 128] ----------------
__global__ __launch_bounds__(256) void bn_stats_kernel(const float* __restrict__ x,
                                                       float* __restrict__ sums,
                                                       float* __restrict__ sumsq) {
  int c = threadIdx.x & 127;
  int rbase = (blockIdx.x * 256 + threadIdx.x) >> 7;
  int stride = (gridDim.x * 256) >> 7;
  float s = 0.f, s2 = 0.f;
  for (int r = rbase; r < NN; r += stride) {
    float v = x[(size_t)r * 128 + c];
    s += v;
    s2 += v * v;
  }
  __shared__ float ls[256], ls2[256];
  ls[threadIdx.x] = s;
  ls2[threadIdx.x] = s2;
  __syncthreads();
  if (threadIdx.x < 128) {
    s = ls[threadIdx.x] + ls[threadIdx.x + 128];
    s2 = ls2[threadIdx.x] + ls2[threadIdx.x + 128];
    atomicAdd(&sums[c], s);
    atomicAdd(&sumsq[c], s2);
  }
}

__global__ __launch_bounds__(128) void bn_finalize_kernel(float* __restrict__ stats,
                                                          const float* __restrict__ gamma,
                                                          const float* __restrict__ beta) {
  int c = threadIdx.x;
  float mu = stats[c] * (1.0f / NN);
  float var = stats[128 + c] * (1.0f / NN) - mu * mu;
  var = fmaxf(var, 0.f);
  float sc = gamma[c] * rsqrtf(var + BN_EPS);
  stats[256 + c] = sc;
  stats[384 + c] = beta[c] - mu * sc;
}

// ---------------- launch ----------------
extern "C" void kernel_launch(void* const* d_in, const int* in_sizes, int n_in,
                              void* d_out, int out_size, void* d_ws, size_t ws_size,
                              hipStream_t stream) {
  const float* feat = (const float*)d_in[0];
  const int* g_src = (const int*)d_in[1];
  const int* g_dst = (const int*)d_in[2];
  const int* k_src = (const int*)d_in[3];
  const int* k_dst = (const int*)d_in[4];
  const float* lw_self_0 = (const float*)d_in[5];
  const float* lw_neigh_0 = (const float*)d_in[6];
  const float* lb_0 = (const float*)d_in[7];
  const float* lw_self_1 = (const float*)d_in[8];
  const float* lw_neigh_1 = (const float*)d_in[9];
  const float* lb_1 = (const float*)d_in[10];
  const float* lw_self_2 = (const float*)d_in[11];
  const float* lw_neigh_2 = (const float*)d_in[12];
  const float* lb_2 = (const float*)d_in[13];
  const float* gw_self_0 = (const float*)d_in[14];
  const float* gw_neigh_0 = (const float*)d_in[15];
  const float* gb_0 = (const float*)d_in[16];
  const float* gw_self_1 = (const float*)d_in[17];
  const float* gw_neigh_1 = (const float*)d_in[18];
  const float* gb_1 = (const float*)d_in[19];
  const float* mlp_w1 = (const float*)d_in[20];
  const float* mlp_b1 = (const float*)d_in[21];
  const float* bn_gamma = (const float*)d_in[22];
  const float* bn_beta = (const float*)d_in[23];
  const float* mlp_w2 = (const float*)d_in[24];
  const float* mlp_b2 = (const float*)d_in[25];
  float* out = (float*)d_out;

  float* ws = (float*)d_ws;
  float* bufA = ws;                          // N*H
  float* bufB = bufA + (size_t)NN * HF;      // N*H
  float* bufC = bufB + (size_t)NN * HF;      // N*H  (agg scratch, then x)
  float* bufD = bufC + (size_t)NN * HF;      // N*H  (local_emb)
  float* invg = bufD + (size_t)NN * HF;      // N
  float* invk = invg + NN;                   // N
  float* stats = invk + NN;                  // 512
  int* cnt_g = (int*)(stats + 512);          // N (count, then cursor)
  int* off_g = cnt_g + NN;                   // N+1
  int* esrc_g = off_g + NN + 1;              // EG
  int* cnt_k = esrc_g + EG;                  // N
  int* off_k = cnt_k + NN;                   // N+1
  int* esrc_k = off_k + NN + 1;              // EK

  dim3 blk(256);
  const dim3 gridH(HF / 64, (NN + 63) / 64);
  const dim3 gridM(MLPH / 64, (NN + 63) / 64);
  const dim3 gridO(COUT / 64, (NN + 63) / 64);
  const int agg128_blocks = (NN + 7) / 8;   // TPN=32, 8 nodes/block
  const int agg256_blocks = (NN + 3) / 4;   // TPN=64, 4 nodes/block

  // ---- CSR build for both graphs ----
  hipMemsetAsync(cnt_g, 0, NN * sizeof(int), stream);
  hipMemsetAsync(cnt_k, 0, NN * sizeof(int), stream);
  count_kernel<<<(EG + 255) / 256, blk, 0, stream>>>(g_dst, EG, cnt_g);
  count_kernel<<<(EK + 255) / 256, blk, 0, stream>>>(k_dst, EK, cnt_k);
  invdeg_kernel<<<(NN + 255) / 256, blk, 0, stream>>>(cnt_g, invg);
  invdeg_kernel<<<(NN + 255) / 256, blk, 0, stream>>>(cnt_k, invk);
  scan_kernel<<<1, 1024, 0, stream>>>(cnt_g, off_g, NN);
  scan_kernel<<<1, 1024, 0, stream>>>(cnt_k, off_k, NN);
  hipMemsetAsync(cnt_g, 0, NN * sizeof(int), stream);
  hipMemsetAsync(cnt_k, 0, NN * sizeof(int), stream);
  fill_kernel<<<(EG + 255) / 256, blk, 0, stream>>>(g_src, g_dst, EG, off_g, cnt_g, esrc_g);
  fill_kernel<<<(EK + 255) / 256, blk, 0, stream>>>(k_src, k_dst, EK, off_k, cnt_k, esrc_k);

  // ---- local layer 0: feat[N,128] -> bufA[N,256], relu ----
  csr_aggregate<7><<<agg128_blocks, blk, 0, stream>>>(feat, off_g, esrc_g, bufC);
  gemm_fused<128, 128, true, true, false><<<gridH, blk, 0, stream>>>(
      feat, bufC, invg, lw_self_0, lw_neigh_0, HF, lb_0, nullptr, nullptr, bufA, HF, NN);

  // ---- local layer 1: bufA -> bufB, relu ----
  csr_aggregate<8><<<agg256_blocks, blk, 0, stream>>>(bufA, off_g, esrc_g, bufC);
  gemm_fused<256, 256, true, true, false><<<gridH, blk, 0, stream>>>(
      bufA, bufC, invg, lw_self_1, lw_neigh_1, HF, lb_1, nullptr, nullptr, bufB, HF, NN);

  // ---- local layer 2: bufB -> bufD (local_emb) ----
  csr_aggregate<8><<<agg256_blocks, blk, 0, stream>>>(bufB, off_g, esrc_g, bufC);
  gemm_fused<256, 256, false, true, false><<<gridH, blk, 0, stream>>>(
      bufB, bufC, invg, lw_self_2, lw_neigh_2, HF, lb_2, nullptr, nullptr, bufD, HF, NN);

  // ---- global layer 0: feat -> bufA, relu ----
  csr_aggregate<7><<<agg128_blocks, blk, 0, stream>>>(feat, off_k, esrc_k, bufC);
  gemm_fused<128, 128, true, true, false><<<gridH, blk, 0, stream>>>(
      feat, bufC, invk, gw_self_0, gw_neigh_0, HF, gb_0, nullptr, nullptr, bufA, HF, NN);

  // ---- global layer 1: bufA -> bufB (global_emb) ----
  csr_aggregate<8><<<agg256_blocks, blk, 0, stream>>>(bufA, off_k, esrc_k, bufC);
  gemm_fused<256, 256, false, true, false><<<gridH, blk, 0, stream>>>(
      bufA, bufC, invk, gw_self_1, gw_neigh_1, HF, gb_1, nullptr, nullptr, bufB, HF, NN);

  // ---- head GEMM1: x = local_emb @ w1[0:256] + global_emb @ w1[256:512] + b1 ----
  gemm_fused<256, 256, false, false, false><<<gridM, blk, 0, stream>>>(
      bufD, bufB, nullptr, mlp_w1, mlp_w1 + 256 * MLPH, MLPH, mlp_b1, nullptr, nullptr,
      bufC, MLPH, NN);

  // ---- BatchNorm stats + finalize ----
  hipMemsetAsync(stats, 0, 2 * 128 * sizeof(float), stream);
  bn_stats_kernel<<<256, blk, 0, stream>>>(bufC, stats, stats + 128);
  bn_finalize_kernel<<<1, 128, 0, stream>>>(stats, bn_gamma, bn_beta);

  // ---- head GEMM2: out = relu(bn(x)) @ w2 + b2 ----
  gemm_fused<128, 0, false, false, true><<<gridO, blk, 0, stream>>>(
      bufC, nullptr, nullptr, mlp_w2, nullptr, COUT, mlp_b2, stats + 256, stats + 384,
      out, COUT, NN);
}

// Round 3
// 681.106 us; speedup vs baseline: 4.7662x; 2.2066x over previous
//
#include <hip/hip_runtime.h>

#define NN   50000
#define IN_F 128
#define HF   256
#define COUT 64
#define MLPH 128
#define EG   600000
#define EK   800000
#define BN_EPS 1e-5f

typedef __attribute__((ext_vector_type(8))) short short8;
typedef __attribute__((ext_vector_type(8))) unsigned short ushort8;
typedef __attribute__((ext_vector_type(4))) float f32x4;

__device__ __forceinline__ unsigned short f2bf(float f) {
  union { float f; unsigned int u; } v; v.f = f;
  unsigned int r = v.u + 0x7FFFu + ((v.u >> 16) & 1u);
  return (unsigned short)(r >> 16);
}
__device__ __forceinline__ float bf2f(unsigned short s) {
  union { unsigned int u; float f; } v; v.u = ((unsigned int)s) << 16;
  return v.f;
}

// ---------------- feat -> bf16 ----------------
__global__ __launch_bounds__(256) void cvt_bf16_kernel(const float* __restrict__ in,
                                                       unsigned short* __restrict__ out,
                                                       int n8) {
  int i = blockIdx.x * 256 + threadIdx.x;
  if (i < n8) {
    float4 a = *reinterpret_cast<const float4*>(&in[i * 8]);
    float4 b = *reinterpret_cast<const float4*>(&in[i * 8 + 4]);
    ushort8 o;
    o[0] = f2bf(a.x); o[1] = f2bf(a.y); o[2] = f2bf(a.z); o[3] = f2bf(a.w);
    o[4] = f2bf(b.x); o[5] = f2bf(b.y); o[6] = f2bf(b.z); o[7] = f2bf(b.w);
    *reinterpret_cast<ushort8*>(&out[i * 8]) = o;
  }
}

// ---------------- weight transpose+convert: dst[c*ldk + kofs + r] = src[r][c] ----
struct WDesc { const float* src; int rows; int cshift; int kofs; int ldk; int dofs; };
struct WPack { WDesc d[12]; };

__global__ __launch_bounds__(256) void transpose_weights_kernel(WPack p,
                                                                unsigned short* __restrict__ dst) {
  WDesc w = p.d[blockIdx.y];
  int total = w.rows << w.cshift;
  int cmask = (1 << w.cshift) - 1;
  for (int idx = blockIdx.x * 256 + threadIdx.x; idx < total; idx += gridDim.x * 256) {
    int r = idx >> w.cshift;
    int c = idx & cmask;
    dst[w.dofs + (size_t)c * w.ldk + w.kofs + r] = f2bf(w.src[idx]);
  }
}

// ---------------- CSR build ----------------
__global__ __launch_bounds__(256) void count_kernel(const int* __restrict__ dst, int E,
                                                    int* __restrict__ cnt) {
  int e = blockIdx.x * 256 + threadIdx.x;
  if (e < E) atomicAdd(&cnt[dst[e]], 1);
}

__global__ __launch_bounds__(256) void invdeg_kernel(const int* __restrict__ cnt,
                                                     float* __restrict__ inv) {
  int i = blockIdx.x * 256 + threadIdx.x;
  if (i < NN) inv[i] = 1.0f / fmaxf((float)cnt[i], 1.0f);
}

__global__ __launch_bounds__(1024) void scan_kernel(const int* __restrict__ cnt,
                                                    int* __restrict__ off, int n) {
  __shared__ int wsum[16];
  __shared__ int carry_s;
  const int tid = threadIdx.x;
  const int wid = tid >> 6, lane = tid & 63;
  if (tid == 0) carry_s = 0;
  __syncthreads();
  for (int base = 0; base < n; base += 1024) {
    int i = base + tid;
    int v = (i < n) ? cnt[i] : 0;
    int x = v;
#pragma unroll
    for (int d = 1; d < 64; d <<= 1) {
      int y = __shfl_up(x, d, 64);
      if (lane >= d) x += y;
    }
    if (lane == 63) wsum[wid] = x;
    __syncthreads();
    if (wid == 0 && lane < 16) {
      int s = wsum[lane];
#pragma unroll
      for (int d = 1; d < 16; d <<= 1) {
        int y = __shfl_up(s, d, 16);
        if (lane >= d) s += y;
      }
      wsum[lane] = s;
    }
    __syncthreads();
    int block_excl = (wid > 0) ? wsum[wid - 1] : 0;
    int incl = x + block_excl + carry_s;
    if (i < n) off[i] = incl - v;
    __syncthreads();
    if (tid == 0) carry_s += wsum[15];
    __syncthreads();
  }
  if (tid == 0) off[n] = carry_s;
}

__global__ __launch_bounds__(256) void fill_kernel(const int* __restrict__ src,
                                                   const int* __restrict__ dst, int E,
                                                   const int* __restrict__ off,
                                                   int* __restrict__ cursor,
                                                   int* __restrict__ esrc) {
  int e = blockIdx.x * 256 + threadIdx.x;
  if (e < E) {
    int d = dst[e];
    int p = atomicAdd(&cursor[d], 1);
    esrc[off[d] + p] = src[e];
  }
}

// ---------------- CSR mean-aggregation (bf16 in, bf16 out) ----------------
// out[v] = bf16( (1/deg) * sum_{u in N(v)} h[u] )
template <int DLOG2>
__global__ __launch_bounds__(256) void csr_aggregate(const unsigned short* __restrict__ h,
                                                     const int* __restrict__ off,
                                                     const int* __restrict__ esrc,
                                                     const float* __restrict__ inv,
                                                     unsigned short* __restrict__ out) {
  constexpr int TPN = (1 << DLOG2) / 8;  // lanes per node, 8 bf16 (16B) each
  constexpr int NPB = 256 / TPN;
  int node = blockIdx.x * NPB + (threadIdx.x / TPN);
  int lane = threadIdx.x & (TPN - 1);
  if (node >= NN) return;
  int s = off[node], e = off[node + 1];
  float acc[8] = {0.f, 0.f, 0.f, 0.f, 0.f, 0.f, 0.f, 0.f};
  int j = s;
  for (; j + 1 < e; j += 2) {
    int s0 = esrc[j], s1 = esrc[j + 1];
    ushort8 v0 = *reinterpret_cast<const ushort8*>(&h[((size_t)s0 << DLOG2) + lane * 8]);
    ushort8 v1 = *reinterpret_cast<const ushort8*>(&h[((size_t)s1 << DLOG2) + lane * 8]);
#pragma unroll
    for (int i = 0; i < 8; ++i) acc[i] += bf2f(v0[i]);
#pragma unroll
    for (int i = 0; i < 8; ++i) acc[i] += bf2f(v1[i]);
  }
  if (j < e) {
    int s0 = esrc[j];
    ushort8 v0 = *reinterpret_cast<const ushort8*>(&h[((size_t)s0 << DLOG2) + lane * 8]);
#pragma unroll
    for (int i = 0; i < 8; ++i) acc[i] += bf2f(v0[i]);
  }
  float sc = inv[node];
  ushort8 o;
#pragma unroll
  for (int i = 0; i < 8; ++i) o[i] = f2bf(acc[i] * sc);
  *reinterpret_cast<ushort8*>(&out[((size_t)node << DLOG2) + lane * 8]) = o;
}

// ---------------- MFMA GEMM ----------------
// out[m][n] = act( sum_{k<K1} A1[m][k] Bt[n][k] + sum_{k<K2} A2[m][k] Bt[n][K1+k] + bias[n] )
// BN1: A1 is f32, element transformed relu(x*bnscale[k]+bnshift[k]) then bf16.
// Layout per v_mfma_f32_16x16x32_bf16: A lane holds row (l&15), k=(l>>4)*8+j;
// B lane holds col (l&15), k=(l>>4)*8+j; D lane holds col (l&15), row=(l>>4)*4+reg.
template <int K1, int K2, bool RELU, bool BN1, bool OUT_BF16>
__global__ __launch_bounds__(256) void gemm_mfma(
    const void* __restrict__ A1v, const void* __restrict__ A2v,
    const unsigned short* __restrict__ Bt, const float* __restrict__ bias,
    const float* __restrict__ bnscale, const float* __restrict__ bnshift,
    void* __restrict__ outv, int ldo, int nrows) {
  constexpr int KTOT = K1 + K2;
  constexpr int KT = KTOT / 64;
  constexpr int LDT = 72;  // bf16 units; 144B row stride -> 2-way (free) on b128 reads
  __shared__ char smem[2 * 64 * LDT * 2];
  unsigned short* As = (unsigned short*)smem;
  unsigned short* Bs = As + 64 * LDT;
  float* Co = (float*)smem;  // 64 x 68 reuse for epilogue
  constexpr int LDC = 68;

  const int t = threadIdx.x;
  const int lane = t & 63;
  const int w = t >> 6;
  const int wm = (w & 1) * 32, wn = (w >> 1) * 32;
  const int row0 = blockIdx.y * 64;
  const int n0 = blockIdx.x * 64;

  const int sr = t >> 2;            // staging row 0..63
  const int skc = (t & 3) * 16;     // staging k-chunk
  int rg = row0 + sr;
  if (rg >= nrows) rg = nrows - 1;

  f32x4 acc[2][2] = {};

  for (int kt = 0; kt < KT; ++kt) {
    const int kbase = kt * 64;
    // ---- stage A tile ----
    if (BN1) {
      const float* xb = (const float*)A1v + (size_t)rg * K1 + kbase + skc;
      ushort8 o0, o1;
#pragma unroll
      for (int i = 0; i < 8; ++i) {
        float v = xb[i] * bnscale[kbase + skc + i] + bnshift[kbase + skc + i];
        o0[i] = f2bf(fmaxf(v, 0.f));
      }
#pragma unroll
      for (int i = 0; i < 8; ++i) {
        float v = xb[8 + i] * bnscale[kbase + skc + 8 + i] + bnshift[kbase + skc + 8 + i];
        o1[i] = f2bf(fmaxf(v, 0.f));
      }
      *reinterpret_cast<ushort8*>(&As[sr * LDT + skc]) = o0;
      *reinterpret_cast<ushort8*>(&As[sr * LDT + skc + 8]) = o1;
    } else {
      const unsigned short* ab;
      if (kbase < K1)
        ab = (const unsigned short*)A1v + (size_t)rg * K1 + kbase + skc;
      else
        ab = (const unsigned short*)A2v + (size_t)rg * K2 + (kbase - K1) + skc;
      int4 p0 = *reinterpret_cast<const int4*>(ab);
      int4 p1 = *reinterpret_cast<const int4*>(ab + 8);
      *reinterpret_cast<int4*>(&As[sr * LDT + skc]) = p0;
      *reinterpret_cast<int4*>(&As[sr * LDT + skc + 8]) = p1;
    }
    // ---- stage B tile (Bt is [Nout][KTOT] bf16 row-major) ----
    {
      const unsigned short* bb = Bt + (size_t)(n0 + sr) * KTOT + kbase + skc;
      int4 p0 = *reinterpret_cast<const int4*>(bb);
      int4 p1 = *reinterpret_cast<const int4*>(bb + 8);
      *reinterpret_cast<int4*>(&Bs[sr * LDT + skc]) = p0;
      *reinterpret_cast<int4*>(&Bs[sr * LDT + skc + 8]) = p1;
    }
    __syncthreads();
    // ---- compute: 2 k-mfma x 2m x 2n ----
#pragma unroll
    for (int kk = 0; kk < 2; ++kk) {
      const int ko = kk * 32 + (lane >> 4) * 8;
      short8 a0 = *reinterpret_cast<const short8*>(&As[(wm + (lane & 15)) * LDT + ko]);
      short8 a1 = *reinterpret_cast<const short8*>(&As[(wm + 16 + (lane & 15)) * LDT + ko]);
      short8 b0 = *reinterpret_cast<const short8*>(&Bs[(wn + (lane & 15)) * LDT + ko]);
      short8 b1 = *reinterpret_cast<const short8*>(&Bs[(wn + 16 + (lane & 15)) * LDT + ko]);
      acc[0][0] = __builtin_amdgcn_mfma_f32_16x16x32_bf16(a0, b0, acc[0][0], 0, 0, 0);
      acc[0][1] = __builtin_amdgcn_mfma_f32_16x16x32_bf16(a0, b1, acc[0][1], 0, 0, 0);
      acc[1][0] = __builtin_amdgcn_mfma_f32_16x16x32_bf16(a1, b0, acc[1][0], 0, 0, 0);
      acc[1][1] = __builtin_amdgcn_mfma_f32_16x16x32_bf16(a1, b1, acc[1][1], 0, 0, 0);
    }
    __syncthreads();
  }

  // ---- epilogue: stage acc to LDS, then coalesced store ----
#pragma unroll
  for (int mi = 0; mi < 2; ++mi)
#pragma unroll
    for (int ni = 0; ni < 2; ++ni) {
      int col = wn + ni * 16 + (lane & 15);
      int rowb = wm + mi * 16 + (lane >> 4) * 4;
#pragma unroll
      for (int j = 0; j < 4; ++j) Co[(rowb + j) * LDC + col] = acc[mi][ni][j];
    }
  __syncthreads();
  {
    int r = row0 + sr;
    if (r < nrows) {
      float v[16];
#pragma unroll
      for (int i = 0; i < 16; ++i) {
        v[i] = Co[sr * LDC + skc + i] + bias[n0 + skc + i];
        if (RELU) v[i] = fmaxf(v[i], 0.f);
      }
      if (OUT_BF16) {
        unsigned short* dst = (unsigned short*)outv + (size_t)r * ldo + n0 + skc;
        ushort8 o0, o1;
#pragma unroll
        for (int i = 0; i < 8; ++i) { o0[i] = f2bf(v[i]); o1[i] = f2bf(v[8 + i]); }
        *reinterpret_cast<ushort8*>(dst) = o0;
        *reinterpret_cast<ushort8*>(dst + 8) = o1;
      } else {
        float* dst = (float*)outv + (size_t)r * ldo + n0 + skc;
#pragma unroll
        for (int i = 0; i < 4; ++i) {
          float4 o = make_float4(v[4 * i], v[4 * i + 1], v[4 * i + 2], v[4 * i + 3]);
          *reinterpret_cast<float4*>(dst + 4 * i) = o;
        }
      }
    }
  }
}

// ---------------- BN stats over columns of x[N, 128] ----------------
__global__ __launch_bounds__(256) void bn_stats_kernel(const float* __restrict__ x,
                                                       float* __restrict__ sums,
                                                       float* __restrict__ sumsq) {
  int c = threadIdx.x & 127;
  int rbase = (blockIdx.x * 256 + threadIdx.x) >> 7;
  int stride = (gridDim.x * 256) >> 7;
  float s = 0.f, s2 = 0.f;
  for (int r = rbase; r < NN; r += stride) {
    float v = x[(size_t)r * 128 + c];
    s += v;
    s2 += v * v;
  }
  __shared__ float ls[256], ls2[256];
  ls[threadIdx.x] = s;
  ls2[threadIdx.x] = s2;
  __syncthreads();
  if (threadIdx.x < 128) {
    s = ls[threadIdx.x] + ls[threadIdx.x + 128];
    s2 = ls2[threadIdx.x] + ls2[threadIdx.x + 128];
    atomicAdd(&sums[c], s);
    atomicAdd(&sumsq[c], s2);
  }
}

__global__ __launch_bounds__(128) void bn_finalize_kernel(float* __restrict__ stats,
                                                          const float* __restrict__ gamma,
                                                          const float* __restrict__ beta) {
  int c = threadIdx.x;
  float mu = stats[c] * (1.0f / NN);
  float var = stats[128 + c] * (1.0f / NN) - mu * mu;
  var = fmaxf(var, 0.f);
  float sc = gamma[c] * rsqrtf(var + BN_EPS);
  stats[256 + c] = sc;
  stats[384 + c] = beta[c] - mu * sc;
}

// ---------------- launch ----------------
extern "C" void kernel_launch(void* const* d_in, const int* in_sizes, int n_in,
                              void* d_out, int out_size, void* d_ws, size_t ws_size,
                              hipStream_t stream) {
  const float* feat = (const float*)d_in[0];
  const int* g_src = (const int*)d_in[1];
  const int* g_dst = (const int*)d_in[2];
  const int* k_src = (const int*)d_in[3];
  const int* k_dst = (const int*)d_in[4];
  const float* mlp_b1 = (const float*)d_in[21];
  const float* bn_gamma = (const float*)d_in[22];
  const float* bn_beta = (const float*)d_in[23];
  const float* mlp_b2 = (const float*)d_in[25];
  const float* lb_0 = (const float*)d_in[7];
  const float* lb_1 = (const float*)d_in[10];
  const float* lb_2 = (const float*)d_in[13];
  const float* gb_0 = (const float*)d_in[16];
  const float* gb_1 = (const float*)d_in[19];
  float* out = (float*)d_out;

  // workspace layout
  float* xf32 = (float*)d_ws;                         // N*128 f32
  float* invg = xf32 + (size_t)NN * 128;              // N
  float* invk = invg + NN;                            // N
  float* stats = invk + NN;                           // 512
  unsigned short* bfA = (unsigned short*)(stats + 512);      // N*256
  unsigned short* bfB = bfA + (size_t)NN * HF;               // N*256
  unsigned short* bfAgg = bfB + (size_t)NN * HF;             // N*256
  unsigned short* bfD = bfAgg + (size_t)NN * HF;             // N*256 (local_emb)
  unsigned short* featbf = bfD + (size_t)NN * HF;            // N*128
  unsigned short* wts = featbf + (size_t)NN * IN_F;          // 598016
  int* cnt_g = (int*)(wts + 598016);
  int* off_g = cnt_g + NN;
  int* esrc_g = off_g + NN + 1;
  int* cnt_k = esrc_g + EG;
  int* off_k = cnt_k + NN;
  int* esrc_k = off_k + NN + 1;

  // weight sub-buffers (ushort offsets)
  const int wL0 = 0, wL1 = 65536, wL2 = 196608, wG0 = 327680, wG1 = 393216,
            wH1 = 524288, wH2 = 589824;

  dim3 blk(256);
  const dim3 gridH(4, (NN + 63) / 64);   // 256-col out
  const dim3 gridM(2, (NN + 63) / 64);   // 128-col out
  const dim3 gridO(1, (NN + 63) / 64);   // 64-col out
  const int agg128_blocks = (NN + 15) / 16;  // TPN=16
  const int agg256_blocks = (NN + 7) / 8;    // TPN=32

  // ---- feat -> bf16, weights -> transposed bf16 ----
  cvt_bf16_kernel<<<(NN * IN_F / 8 + 255) / 256, blk, 0, stream>>>(feat, featbf, NN * IN_F / 8);
  {
    WPack p;
    // src, rows, cshift(cols), kofs, ldk, dofs
    p.d[0] = {(const float*)d_in[5], 128, 8, 0, 256, wL0};
    p.d[1] = {(const float*)d_in[6], 128, 8, 128, 256, wL0};
    p.d[2] = {(const float*)d_in[8], 256, 8, 0, 512, wL1};
    p.d[3] = {(const float*)d_in[9], 256, 8, 256, 512, wL1};
    p.d[4] = {(const float*)d_in[11], 256, 8, 0, 512, wL2};
    p.d[5] = {(const float*)d_in[12], 256, 8, 256, 512, wL2};
    p.d[6] = {(const float*)d_in[14], 128, 8, 0, 256, wG0};
    p.d[7] = {(const float*)d_in[15], 128, 8, 128, 256, wG0};
    p.d[8] = {(const float*)d_in[17], 256, 8, 0, 512, wG1};
    p.d[9] = {(const float*)d_in[18], 256, 8, 256, 512, wG1};
    p.d[10] = {(const float*)d_in[20], 512, 7, 0, 512, wH1};
    p.d[11] = {(const float*)d_in[24], 128, 6, 0, 128, wH2};
    transpose_weights_kernel<<<dim3(32, 12), blk, 0, stream>>>(p, wts);
  }

  // ---- CSR build ----
  hipMemsetAsync(cnt_g, 0, NN * sizeof(int), stream);
  hipMemsetAsync(cnt_k, 0, NN * sizeof(int), stream);
  count_kernel<<<(EG + 255) / 256, blk, 0, stream>>>(g_dst, EG, cnt_g);
  count_kernel<<<(EK + 255) / 256, blk, 0, stream>>>(k_dst, EK, cnt_k);
  invdeg_kernel<<<(NN + 255) / 256, blk, 0, stream>>>(cnt_g, invg);
  invdeg_kernel<<<(NN + 255) / 256, blk, 0, stream>>>(cnt_k, invk);
  scan_kernel<<<1, 1024, 0, stream>>>(cnt_g, off_g, NN);
  scan_kernel<<<1, 1024, 0, stream>>>(cnt_k, off_k, NN);
  hipMemsetAsync(cnt_g, 0, NN * sizeof(int), stream);
  hipMemsetAsync(cnt_k, 0, NN * sizeof(int), stream);
  fill_kernel<<<(EG + 255) / 256, blk, 0, stream>>>(g_src, g_dst, EG, off_g, cnt_g, esrc_g);
  fill_kernel<<<(EK + 255) / 256, blk, 0, stream>>>(k_src, k_dst, EK, off_k, cnt_k, esrc_k);

  // ---- local layer 0 ----
  csr_aggregate<7><<<agg128_blocks, blk, 0, stream>>>(featbf, off_g, esrc_g, invg, bfAgg);
  gemm_mfma<128, 128, true, false, true><<<gridH, blk, 0, stream>>>(
      featbf, bfAgg, wts + wL0, lb_0, nullptr, nullptr, bfA, HF, NN);
  // ---- local layer 1 ----
  csr_aggregate<8><<<agg256_blocks, blk, 0, stream>>>(bfA, off_g, esrc_g, invg, bfAgg);
  gemm_mfma<256, 256, true, false, true><<<gridH, blk, 0, stream>>>(
      bfA, bfAgg, wts + wL1, lb_1, nullptr, nullptr, bfB, HF, NN);
  // ---- local layer 2 -> local_emb ----
  csr_aggregate<8><<<agg256_blocks, blk, 0, stream>>>(bfB, off_g, esrc_g, invg, bfAgg);
  gemm_mfma<256, 256, false, false, true><<<gridH, blk, 0, stream>>>(
      bfB, bfAgg, wts + wL2, lb_2, nullptr, nullptr, bfD, HF, NN);
  // ---- global layer 0 ----
  csr_aggregate<7><<<agg128_blocks, blk, 0, stream>>>(featbf, off_k, esrc_k, invk, bfAgg);
  gemm_mfma<128, 128, true, false, true><<<gridH, blk, 0, stream>>>(
      featbf, bfAgg, wts + wG0, gb_0, nullptr, nullptr, bfA, HF, NN);
  // ---- global layer 1 -> global_emb ----
  csr_aggregate<8><<<agg256_blocks, blk, 0, stream>>>(bfA, off_k, esrc_k, invk, bfAgg);
  gemm_mfma<256, 256, false, false, true><<<gridH, blk, 0, stream>>>(
      bfA, bfAgg, wts + wG1, gb_1, nullptr, nullptr, bfB, HF, NN);

  // ---- head GEMM1: x = [local_emb | global_emb] @ w1 + b1 (f32 out) ----
  gemm_mfma<256, 256, false, false, false><<<gridM, blk, 0, stream>>>(
      bfD, bfB, wts + wH1, mlp_b1, nullptr, nullptr, xf32, MLPH, NN);

  // ---- BatchNorm ----
  hipMemsetAsync(stats, 0, 2 * 128 * sizeof(float), stream);
  bn_stats_kernel<<<256, blk, 0, stream>>>(xf32, stats, stats + 128);
  bn_finalize_kernel<<<1, 128, 0, stream>>>(stats, bn_gamma, bn_beta);

  // ---- head GEMM2: out = relu(bn(x)) @ w2 + b2 ----
  gemm_mfma<128, 0, false, true, false><<<gridO, blk, 0, stream>>>(
      xf32, nullptr, wts + wH2, mlp_b2, stats + 256, stats + 384, out, COUT, NN);
}